// Round 12
// baseline (252.482 us; speedup 1.0000x reference)
//
#include <hip/hip_runtime.h>
#include <stdint.h>

#define D_EMB   64
#define N_ROWS  4096
#define DIM     512
#define KNEG    64
#define P_PAIRS 62
#define BPE     16                      // chunks per embedding in pass1
#define RPB     (N_ROWS / BPE)          // 256 rows per chunk
#define NCHUNK  (D_EMB * BPE)           // 1024 chunk blocks
#define EPSN    1e-8f
#define INV_T   10.0f
#define NEGINF  (-1e30f)

typedef float f32x4 __attribute__((ext_vector_type(4)));  // nt-load-compatible

// ---------------- threefry-2x32-20 (matches JAX partitionable path) ---------
__device__ __forceinline__ uint32_t rotl32(uint32_t v, uint32_t r) {
  return (v << r) | (v >> (32u - r));
}

__device__ __forceinline__ void threefry(uint32_t k0, uint32_t k1,
                                         uint32_t c0, uint32_t c1,
                                         uint32_t& o0, uint32_t& o1) {
  uint32_t ks0 = k0, ks1 = k1, ks2 = k0 ^ k1 ^ 0x1BD11BDAu;
  uint32_t x0 = c0 + ks0, x1 = c1 + ks1;
#define RG(a,b,c,d) \
  x0 += x1; x1 = rotl32(x1,a); x1 ^= x0; \
  x0 += x1; x1 = rotl32(x1,b); x1 ^= x0; \
  x0 += x1; x1 = rotl32(x1,c); x1 ^= x0; \
  x0 += x1; x1 = rotl32(x1,d); x1 ^= x0;
  RG(13,15,26,6)   x0 += ks1; x1 += ks2 + 1u;
  RG(17,29,16,24)  x0 += ks2; x1 += ks0 + 2u;
  RG(13,15,26,6)   x0 += ks0; x1 += ks1 + 3u;
  RG(17,29,16,24)  x0 += ks1; x1 += ks2 + 4u;
  RG(13,15,26,6)   x0 += ks2; x1 += ks0 + 5u;
#undef RG
  o0 = x0; o1 = x1;
}

// ---------------- kernel 1: stream (nt) + last-arrival embedding finalize ---
// grid: NCHUNK+1 blocks, 256 threads. Block NCHUNK computes the pos-pair.
// Finalize is barrier-free (pop-loop topk) so the post-stream tail is ~5us.
__global__ __launch_bounds__(256, 4) void k_p1e(const float* __restrict__ I,
                                                const float* __restrict__ g1,
                                                const float* __restrict__ g2,
                                                float* __restrict__ partial,
                                                float* __restrict__ norms,
                                                float* __restrict__ samples,
                                                float* __restrict__ snorm,
                                                float* __restrict__ posp,
                                                int* __restrict__ cnt) {
  const int t = threadIdx.x, lane = t & 63, w = t >> 6;
  __shared__ float lds[4 * DIM];       // 8 KB
  __shared__ float nlds[RPB];
  __shared__ float rA[4], rB[4], rC[4];
  __shared__ int   flag;
  __shared__ float cval[4 * KNEG];
  __shared__ int   cidx[4 * KNEG];
  __shared__ int   topidx[KNEG];

  if (blockIdx.x == NCHUNK) {          // positive-pair scalar (reads g1,g2 only)
    float x0 = g1[t], x1 = g1[256 + t], y0 = g2[t], y1 = g2[256 + t];
    float d = x0*y0 + x1*y1, sa = x0*x0 + x1*x1, sb = y0*y0 + y1*y1;
#pragma unroll
    for (int off = 32; off; off >>= 1) {
      d  += __shfl_xor(d, off);
      sa += __shfl_xor(sa, off);
      sb += __shfl_xor(sb, off);
    }
    if (lane == 0) { rA[w] = d; rB[w] = sa; rC[w] = sb; }
    __syncthreads();
    if (t == 0) {
      float dt = rA[0] + rA[1] + rA[2] + rA[3];
      float s1 = rB[0] + rB[1] + rB[2] + rB[3];
      float s2 = rC[0] + rC[1] + rC[2] + rC[3];
      posp[0] = dt / (fmaxf(sqrtf(s1), EPSN) * fmaxf(sqrtf(s2), EPSN)) * INV_T;
    }
    return;
  }

  // ===== phase 1: stream one 256-row chunk (nt loads, 16 in flight) =====
  const int e = blockIdx.x >> 4, b = blockIdx.x & 15;
  const f32x4* base4 = reinterpret_cast<const f32x4*>(I) + (size_t)e * N_ROWS * (DIM / 4);
  const int nbase = b * RPB;
  const int wrow = w * (RPB / 4);
  float acc[8] = {0.f,0.f,0.f,0.f,0.f,0.f,0.f,0.f};

#define NTL(p) __builtin_nontemporal_load(p)
  for (int i = 0; i < 8; ++i) {                // 8 iters x 8 rows
    const int lr = wrow + i * 8;
    const int idx = (nbase + lr) * (DIM / 4) + lane;
    f32x4 A0 = NTL(base4 + idx + 0*128), B0 = NTL(base4 + idx + 0*128 + 64);
    f32x4 A1 = NTL(base4 + idx + 1*128), B1 = NTL(base4 + idx + 1*128 + 64);
    f32x4 A2 = NTL(base4 + idx + 2*128), B2 = NTL(base4 + idx + 2*128 + 64);
    f32x4 A3 = NTL(base4 + idx + 3*128), B3 = NTL(base4 + idx + 3*128 + 64);
    f32x4 A4 = NTL(base4 + idx + 4*128), B4 = NTL(base4 + idx + 4*128 + 64);
    f32x4 A5 = NTL(base4 + idx + 5*128), B5 = NTL(base4 + idx + 5*128 + 64);
    f32x4 A6 = NTL(base4 + idx + 6*128), B6 = NTL(base4 + idx + 6*128 + 64);
    f32x4 A7 = NTL(base4 + idx + 7*128), B7 = NTL(base4 + idx + 7*128 + 64);

    acc[0] += A0.x + A1.x + A2.x + A3.x + A4.x + A5.x + A6.x + A7.x;
    acc[1] += A0.y + A1.y + A2.y + A3.y + A4.y + A5.y + A6.y + A7.y;
    acc[2] += A0.z + A1.z + A2.z + A3.z + A4.z + A5.z + A6.z + A7.z;
    acc[3] += A0.w + A1.w + A2.w + A3.w + A4.w + A5.w + A6.w + A7.w;
    acc[4] += B0.x + B1.x + B2.x + B3.x + B4.x + B5.x + B6.x + B7.x;
    acc[5] += B0.y + B1.y + B2.y + B3.y + B4.y + B5.y + B6.y + B7.y;
    acc[6] += B0.z + B1.z + B2.z + B3.z + B4.z + B5.z + B6.z + B7.z;
    acc[7] += B0.w + B1.w + B2.w + B3.w + B4.w + B5.w + B6.w + B7.w;

#define SQ(r) (A##r.x*A##r.x + A##r.y*A##r.y + A##r.z*A##r.z + A##r.w*A##r.w \
             + B##r.x*B##r.x + B##r.y*B##r.y + B##r.z*B##r.z + B##r.w*B##r.w)
    float s0 = SQ(0), s1 = SQ(1), s2 = SQ(2), s3 = SQ(3);
    float s4 = SQ(4), s5 = SQ(5), s6 = SQ(6), s7 = SQ(7);
#undef SQ
#pragma unroll
    for (int off = 32; off; off >>= 1) {
      s0 += __shfl_xor(s0, off); s1 += __shfl_xor(s1, off);
      s2 += __shfl_xor(s2, off); s3 += __shfl_xor(s3, off);
      s4 += __shfl_xor(s4, off); s5 += __shfl_xor(s5, off);
      s6 += __shfl_xor(s6, off); s7 += __shfl_xor(s7, off);
    }
    if (lane == 0) {
      nlds[lr]     = sqrtf(s0); nlds[lr + 1] = sqrtf(s1);
      nlds[lr + 2] = sqrtf(s2); nlds[lr + 3] = sqrtf(s3);
      nlds[lr + 4] = sqrtf(s4); nlds[lr + 5] = sqrtf(s5);
      nlds[lr + 6] = sqrtf(s6); nlds[lr + 7] = sqrtf(s7);
    }
  }

  const int p0 = 4 * lane;
#pragma unroll
  for (int q = 0; q < 4; ++q) {
    lds[w * DIM + p0 + q]       = acc[q];
    lds[w * DIM + 256 + p0 + q] = acc[4 + q];
  }
  __syncthreads();
  {
    float s0 = lds[t] + lds[DIM + t] + lds[2*DIM + t] + lds[3*DIM + t];
    float s1 = lds[256 + t] + lds[DIM + 256 + t] + lds[2*DIM + 256 + t] + lds[3*DIM + 256 + t];
    float* po = partial + (size_t)blockIdx.x * DIM;
    po[t] = s0;
    po[256 + t] = s1;
    norms[e * N_ROWS + nbase + t] = nlds[t];
  }

  // ===== last-arriving block of this embedding finalizes it =====
  __syncthreads();
  if (t == 0) {
    int old = __hip_atomic_fetch_add(&cnt[e], 1, __ATOMIC_ACQ_REL,
                                     __HIP_MEMORY_SCOPE_AGENT);
    flag = (old == BPE - 1) ? 1 : 0;
  }
  __syncthreads();
  const int trig = flag;
  __syncthreads();
  if (!trig) return;
  __builtin_amdgcn_fence(__ATOMIC_ACQUIRE, "agent");

  // ---- top-64: per-wave pop-loop (no barriers, no per-lane sort) ----
  // wave w owns rows [w*1024, w*1024+1024); lane holds 16 (stride-64)
  {
    float v[16];
    const int rb = e * N_ROWS + w * 1024 + lane;
#pragma unroll
    for (int q = 0; q < 16; ++q) v[q] = norms[rb + q * 64];
    float lmax = v[0]; int lq = 0;
#pragma unroll
    for (int q = 1; q < 16; ++q)
      if (v[q] > lmax) { lmax = v[q]; lq = q; }
    int lidx = w * 1024 + lq * 64 + lane;

    for (int k = 0; k < KNEG; ++k) {
      float bv = lmax; int bi = lidx;
#pragma unroll
      for (int off = 32; off; off >>= 1) {
        float ov = __shfl_xor(bv, off);
        int   oi = __shfl_xor(bi, off);
        if (ov > bv || (ov == bv && oi < bi)) { bv = ov; bi = oi; }
      }
      if (lane == 0) { cval[w * KNEG + k] = bv; cidx[w * KNEG + k] = bi; }
      if (lmax == bv && lidx == bi) {      // owner removes & rescans its 16
        v[(bi & 1023) >> 6] = NEGINF;
        lmax = v[0]; lq = 0;
#pragma unroll
        for (int q = 1; q < 16; ++q)
          if (v[q] > lmax) { lmax = v[q]; lq = q; }
        lidx = w * 1024 + lq * 64 + lane;
      }
    }
  }
  __syncthreads();

  // lanes 0-3 of wave 0: 64-step 4-way merge of the sorted lists
  if (w == 0) {
    int p = 0;
    float hv = (lane < 4) ? cval[lane * KNEG] : NEGINF;
    int   hi = (lane < 4) ? cidx[lane * KNEG] : 0x7fffffff;
    for (int k = 0; k < KNEG; ++k) {
      float bv = hv; int bi = hi;
#pragma unroll
      for (int off = 2; off; off >>= 1) {          // butterfly within 4 lanes
        float ov = __shfl_xor(bv, off, 4);
        int   oi = __shfl_xor(bi, off, 4);
        if (ov > bv || (ov == bv && oi < bi)) { bv = ov; bi = oi; }
      }
      if (lane == 0) topidx[k] = bi;
      if (lane < 4 && hv == bv && hi == bi) {      // winner list advances
        ++p;
        hv = (p < KNEG) ? cval[lane * KNEG + p] : NEGINF;
        hi = (p < KNEG) ? cidx[lane * KNEG + p] : 0x7fffffff;
      }
    }
  }
  __syncthreads();

  // ---- fold partials -> sums (cols t, t+256) ----
  float s0 = 0.f, s1 = 0.f;
  for (int b2 = 0; b2 < BPE; ++b2) {
    const float* pp = partial + (size_t)(e * BPE + b2) * DIM;
    s0 += pp[t];
    s1 += pp[256 + t];
  }
  // ---- gather top-64 rows (nt), subtract ----
  const float* rbase = I + (size_t)e * N_ROWS * DIM;
  float a0 = 0.f, a1 = 0.f;
#pragma unroll 4
  for (int k = 0; k < KNEG; ++k) {
    const float* r = rbase + (size_t)topidx[k] * DIM;
    a0 += NTL(r + t);
    a1 += NTL(r + 256 + t);
  }
#undef NTL
  float sn0 = s0 - a0, sn1 = s1 - a1;

  float q1 = s0 * s0 + s1 * s1, q2 = sn0 * sn0 + sn1 * sn1;
#pragma unroll
  for (int off = 32; off; off >>= 1) {
    q1 += __shfl_xor(q1, off);
    q2 += __shfl_xor(q2, off);
  }
  if (lane == 0) { rA[w] = q1; rB[w] = q2; }
  __syncthreads();
  if (t == 0) {
    float n1 = rA[0] + rA[1] + rA[2] + rA[3];
    float n2 = rB[0] + rB[1] + rB[2] + rB[3];
    snorm[e]         = fmaxf(sqrtf(n1), EPSN);
    snorm[D_EMB + e] = fmaxf(sqrtf(n2), EPSN);
  }
  samples[(size_t)e * DIM + t]                 = s0;
  samples[(size_t)e * DIM + 256 + t]           = s1;
  samples[(size_t)(D_EMB + e) * DIM + t]       = sn0;
  samples[(size_t)(D_EMB + e) * DIM + 256 + t] = sn1;
}

// ---------------- kernel 2: select + sims + LSE + loss + final sum ----------
__global__ __launch_bounds__(256) void k_p3p4(const float* __restrict__ samples,
                                              const float* __restrict__ snorm,
                                              const float* __restrict__ posp,
                                              float* __restrict__ pairloss,
                                              int* __restrict__ cnt2,
                                              float* __restrict__ out) {
  const int p = blockIdx.x;
  const int t = threadIdx.x, lane = t & 63, w = t >> 6;
  __shared__ uint32_t bits[126];
  __shared__ uint32_t sk[2];
  __shared__ int      sel[KNEG];
  __shared__ float    simi[KNEG], simj[KNEG];
  __shared__ int      flag;

  if (t == 0) {
    uint32_t kh, kl, a, b;
    threefry(0u, 42u, 0u, (uint32_t)p, kh, kl);   // keys[p] = split(key(42),62)[p]
    threefry(kh, kl, 0u, 1u, a, b);               // subkey = split(keys[p])[1]
    sk[0] = a; sk[1] = b;
  }
  __syncthreads();
  if (t < 126) {
    uint32_t a, b;
    threefry(sk[0], sk[1], 0u, (uint32_t)t, a, b);
    bits[t] = a ^ b;                              // partitionable 32-bit path
  }
  __syncthreads();
  if (t < 126) {
    const uint32_t myb = bits[t];
    int rank = 0;
    for (int j = 0; j < 126; ++j) {
      const uint32_t bj = bits[j];
      rank += ((bj < myb) || (bj == myb && j < t)) ? 1 : 0;
    }
    if (rank < KNEG) {
      int vv = t + (t >= p ? 1 : 0);              // cand mapping: skip i=p
      vv += (vv >= p + 2 ? 1 : 0);                // then skip j=p+2
      sel[rank] = vv;
    }
  }
  __syncthreads();

  const float4* S = reinterpret_cast<const float4*>(samples);
  const float4 siA = S[p * 128 + lane],       siB = S[p * 128 + 64 + lane];
  const float4 sjA = S[(p + 2) * 128 + lane], sjB = S[(p + 2) * 128 + 64 + lane];
  const float ni = snorm[p], nj = snorm[p + 2];
  for (int k = w; k < KNEG; k += 4) {
    const int r = sel[k];
    const float4 vA = S[r * 128 + lane], vB = S[r * 128 + 64 + lane];
    float di = siA.x*vA.x + siA.y*vA.y + siA.z*vA.z + siA.w*vA.w
             + siB.x*vB.x + siB.y*vB.y + siB.z*vB.z + siB.w*vB.w;
    float dj = sjA.x*vA.x + sjA.y*vA.y + sjA.z*vA.z + sjA.w*vA.w
             + sjB.x*vB.x + sjB.y*vB.y + sjB.z*vB.z + sjB.w*vB.w;
#pragma unroll
    for (int off = 32; off; off >>= 1) {
      di += __shfl_xor(di, off);
      dj += __shfl_xor(dj, off);
    }
    if (lane == 0) {
      const float nr = snorm[r];
      simi[k] = di / (ni * nr) * INV_T;
      simj[k] = dj / (nj * nr) * INV_T;
    }
  }
  __syncthreads();
  if (t < KNEG) {                                  // wave 0 only
    const float xi = simi[t], xj = simj[t];
    float mi = xi, mj = xj;
#pragma unroll
    for (int off = 32; off; off >>= 1) {
      mi = fmaxf(mi, __shfl_xor(mi, off));
      mj = fmaxf(mj, __shfl_xor(mj, off));
    }
    float ei = expf(xi - mi), ej = expf(xj - mj);
#pragma unroll
    for (int off = 32; off; off >>= 1) {
      ei += __shfl_xor(ei, off);
      ej += __shfl_xor(ej, off);
    }
    if (t == 0) {
      const float pos = posp[0];
      const float lsei = mi + logf(ei), lsej = mj + logf(ej);
      const float li = fmaxf(pos, lsei) + log1pf(expf(-fabsf(pos - lsei))) - pos;
      const float lj = fmaxf(pos, lsej) + log1pf(expf(-fabsf(pos - lsej))) - pos;
      pairloss[p] = li + lj;
    }
  }
  __syncthreads();

  // ---- last-arriving pair block does the final sum ----
  if (t == 0) {
    int old = __hip_atomic_fetch_add(cnt2, 1, __ATOMIC_ACQ_REL,
                                     __HIP_MEMORY_SCOPE_AGENT);
    flag = (old == P_PAIRS - 1) ? 1 : 0;
  }
  __syncthreads();
  const int trig = flag;
  __syncthreads();
  if (!trig) return;
  __builtin_amdgcn_fence(__ATOMIC_ACQUIRE, "agent");
  if (t < 64) {
    float vv = (t < P_PAIRS) ? pairloss[t] : 0.f;
#pragma unroll
    for (int off = 32; off; off >>= 1) vv += __shfl_xor(vv, off);
    if (t == 0) out[0] = vv;
  }
}

extern "C" void kernel_launch(void* const* d_in, const int* in_sizes, int n_in,
                              void* d_out, int out_size, void* d_ws, size_t ws_size,
                              hipStream_t stream) {
  const float* I  = (const float*)d_in[0];
  const float* g1 = (const float*)d_in[2];
  const float* g2 = (const float*)d_in[3];
  float* out = (float*)d_out;

  float* ws = (float*)d_ws;
  float* norms    = ws;                                   // 64*4096     = 262144
  float* partial  = ws + 262144;                          // 1024*512    = 524288
  float* samples  = partial + 524288;                     // 128*512     = 65536
  float* snorm    = samples + 65536;                      // 128
  float* posp     = snorm + 128;                          // 1 (+pad)
  float* pairloss = posp + 4;                             // 62 (+pad 64)
  int*   cnt      = (int*)(pairloss + 64);                // 64 ints
  int*   cnt2     = cnt + 64;                             // 1 int

  hipMemsetAsync(cnt, 0, 65 * sizeof(int), stream);       // re-zero each replay

  k_p1e <<<NCHUNK + 1, 256, 0, stream>>>(I, g1, g2, partial, norms,
                                         samples, snorm, posp, cnt);
  k_p3p4<<<P_PAIRS,    256, 0, stream>>>(samples, snorm, posp, pairloss,
                                         cnt2, out);
}

// Round 13
// 175.552 us; speedup vs baseline: 1.4382x; 1.4382x over previous
//
#include <hip/hip_runtime.h>
#include <stdint.h>

#define D_EMB   64
#define N_ROWS  4096
#define DIM     512
#define KNEG    64
#define P_PAIRS 62
#define BPE     16                      // chunks per embedding in pass1
#define RPB     (N_ROWS / BPE)          // 256 rows per chunk
#define NCHUNK  (D_EMB * BPE)           // 1024 blocks (= 4 blocks/CU exactly)
#define EPSN    1e-8f
#define INV_T   10.0f
#define NEGINF  (-1e30f)

typedef float f32x4 __attribute__((ext_vector_type(4)));  // nt-load-compatible

// ---------------- threefry-2x32-20 (matches JAX partitionable path) ---------
__device__ __forceinline__ uint32_t rotl32(uint32_t v, uint32_t r) {
  return (v << r) | (v >> (32u - r));
}

__device__ __forceinline__ void threefry(uint32_t k0, uint32_t k1,
                                         uint32_t c0, uint32_t c1,
                                         uint32_t& o0, uint32_t& o1) {
  uint32_t ks0 = k0, ks1 = k1, ks2 = k0 ^ k1 ^ 0x1BD11BDAu;
  uint32_t x0 = c0 + ks0, x1 = c1 + ks1;
#define RG(a,b,c,d) \
  x0 += x1; x1 = rotl32(x1,a); x1 ^= x0; \
  x0 += x1; x1 = rotl32(x1,b); x1 ^= x0; \
  x0 += x1; x1 = rotl32(x1,c); x1 ^= x0; \
  x0 += x1; x1 = rotl32(x1,d); x1 ^= x0;
  RG(13,15,26,6)   x0 += ks1; x1 += ks2 + 1u;
  RG(17,29,16,24)  x0 += ks2; x1 += ks0 + 2u;
  RG(13,15,26,6)   x0 += ks0; x1 += ks1 + 3u;
  RG(17,29,16,24)  x0 += ks1; x1 += ks2 + 4u;
  RG(13,15,26,6)   x0 += ks2; x1 += ks0 + 5u;
#undef RG
  o0 = x0; o1 = x1;
}

// ---------------- pass 1: row norms + per-block partial sums ----------------
// grid: 1024 blocks, 256 threads, __launch_bounds__(256,4) -> 128-VGPR cap.
// 16 x 1KB NONTEMPORAL loads in flight per wave.
__global__ __launch_bounds__(256, 4) void k_pass1(const float* __restrict__ I,
                                                  float* __restrict__ partial,
                                                  float* __restrict__ norms) {
  const int e = blockIdx.x >> 4, b = blockIdx.x & 15;
  const int t = threadIdx.x, lane = t & 63, w = t >> 6;
  const f32x4* base4 = reinterpret_cast<const f32x4*>(I) + (size_t)e * N_ROWS * (DIM / 4);
  const int nbase = b * RPB;
  const int wrow = w * (RPB / 4);              // this wave's first local row (64 rows)
  __shared__ float lds[4 * DIM];
  __shared__ float nlds[RPB];
  float acc[8] = {0.f,0.f,0.f,0.f,0.f,0.f,0.f,0.f};

#define NTL(p) __builtin_nontemporal_load(p)
  for (int i = 0; i < 8; ++i) {                // 8 iters x 8 rows
    const int lr = wrow + i * 8;               // local row of first of the 8
    const int idx = (nbase + lr) * (DIM / 4) + lane;   // 32-bit element index
    // 16 nt loads issued back-to-back (16 KB in flight per wave)
    f32x4 A0 = NTL(base4 + idx + 0*128), B0 = NTL(base4 + idx + 0*128 + 64);
    f32x4 A1 = NTL(base4 + idx + 1*128), B1 = NTL(base4 + idx + 1*128 + 64);
    f32x4 A2 = NTL(base4 + idx + 2*128), B2 = NTL(base4 + idx + 2*128 + 64);
    f32x4 A3 = NTL(base4 + idx + 3*128), B3 = NTL(base4 + idx + 3*128 + 64);
    f32x4 A4 = NTL(base4 + idx + 4*128), B4 = NTL(base4 + idx + 4*128 + 64);
    f32x4 A5 = NTL(base4 + idx + 5*128), B5 = NTL(base4 + idx + 5*128 + 64);
    f32x4 A6 = NTL(base4 + idx + 6*128), B6 = NTL(base4 + idx + 6*128 + 64);
    f32x4 A7 = NTL(base4 + idx + 7*128), B7 = NTL(base4 + idx + 7*128 + 64);

    acc[0] += A0.x + A1.x + A2.x + A3.x + A4.x + A5.x + A6.x + A7.x;
    acc[1] += A0.y + A1.y + A2.y + A3.y + A4.y + A5.y + A6.y + A7.y;
    acc[2] += A0.z + A1.z + A2.z + A3.z + A4.z + A5.z + A6.z + A7.z;
    acc[3] += A0.w + A1.w + A2.w + A3.w + A4.w + A5.w + A6.w + A7.w;
    acc[4] += B0.x + B1.x + B2.x + B3.x + B4.x + B5.x + B6.x + B7.x;
    acc[5] += B0.y + B1.y + B2.y + B3.y + B4.y + B5.y + B6.y + B7.y;
    acc[6] += B0.z + B1.z + B2.z + B3.z + B4.z + B5.z + B6.z + B7.z;
    acc[7] += B0.w + B1.w + B2.w + B3.w + B4.w + B5.w + B6.w + B7.w;

#define SQ(r) (A##r.x*A##r.x + A##r.y*A##r.y + A##r.z*A##r.z + A##r.w*A##r.w \
             + B##r.x*B##r.x + B##r.y*B##r.y + B##r.z*B##r.z + B##r.w*B##r.w)
    float s0 = SQ(0), s1 = SQ(1), s2 = SQ(2), s3 = SQ(3);
    float s4 = SQ(4), s5 = SQ(5), s6 = SQ(6), s7 = SQ(7);
#undef SQ
#pragma unroll
    for (int off = 32; off; off >>= 1) {       // 8 independent chains interleave
      s0 += __shfl_xor(s0, off); s1 += __shfl_xor(s1, off);
      s2 += __shfl_xor(s2, off); s3 += __shfl_xor(s3, off);
      s4 += __shfl_xor(s4, off); s5 += __shfl_xor(s5, off);
      s6 += __shfl_xor(s6, off); s7 += __shfl_xor(s7, off);
    }
    if (lane == 0) {
      nlds[lr]     = sqrtf(s0); nlds[lr + 1] = sqrtf(s1);
      nlds[lr + 2] = sqrtf(s2); nlds[lr + 3] = sqrtf(s3);
      nlds[lr + 4] = sqrtf(s4); nlds[lr + 5] = sqrtf(s5);
      nlds[lr + 6] = sqrtf(s6); nlds[lr + 7] = sqrtf(s7);
    }
  }
#undef NTL

  const int p0 = 4 * lane;
#pragma unroll
  for (int q = 0; q < 4; ++q) {
    lds[w * DIM + p0 + q]       = acc[q];
    lds[w * DIM + 256 + p0 + q] = acc[4 + q];
  }
  __syncthreads();
  float s0 = lds[t] + lds[DIM + t] + lds[2*DIM + t] + lds[3*DIM + t];
  float s1 = lds[256 + t] + lds[DIM + 256 + t] + lds[2*DIM + 256 + t] + lds[3*DIM + 256 + t];
  float* po = partial + (size_t)blockIdx.x * DIM;
  po[t] = s0;
  po[256 + t] = s1;
  norms[e * N_ROWS + nbase + t] = nlds[t];     // 256 norms per block
}

// sorting-network compare-exchange: desc by val, asc by idx (total order)
#define CE(i, j) \
  { bool sw = (v##i < v##j) || (v##i == v##j && d##i > d##j);          \
    float tv = sw ? v##j : v##i; float uv = sw ? v##i : v##j;          \
    int   td = sw ? d##j : d##i; int   ud = sw ? d##i : d##j;          \
    v##i = tv; v##j = uv; d##i = td; d##j = ud; }

// ---------------- kernel 2: per-embedding top64 + fold + sumneg + norms -----
// grid: D_EMB+1 blocks, 512 threads. Block D_EMB: positive pair + cnt2=0.
__global__ __launch_bounds__(512) void k_embed(const float* __restrict__ I,
                                               const float* __restrict__ partial,
                                               const float* __restrict__ norms,
                                               const float* __restrict__ g1,
                                               const float* __restrict__ g2,
                                               float* __restrict__ samples,
                                               float* __restrict__ snorm,
                                               float* __restrict__ posp,
                                               int* __restrict__ cnt2) {
  const int e = blockIdx.x;
  const int t = threadIdx.x, lane = t & 63, w = t >> 6;
  __shared__ float rA[8], rB[8], rC[8];

  if (e == D_EMB) {
    if (t == 0) cnt2[0] = 0;            // arm k_p3p4's last-block counter
    float x = g1[t], y = g2[t];
    float d = x * y, sa = x * x, sb = y * y;
#pragma unroll
    for (int off = 32; off; off >>= 1) {
      d  += __shfl_xor(d, off);
      sa += __shfl_xor(sa, off);
      sb += __shfl_xor(sb, off);
    }
    if (lane == 0) { rA[w] = d; rB[w] = sa; rC[w] = sb; }
    __syncthreads();
    if (t == 0) {
      float dt = 0.f, s1 = 0.f, s2 = 0.f;
      for (int q = 0; q < 8; ++q) { dt += rA[q]; s1 += rB[q]; s2 += rC[q]; }
      posp[0] = dt / (fmaxf(sqrtf(s1), EPSN) * fmaxf(sqrtf(s2), EPSN)) * INV_T;
    }
    return;
  }

  // ===== top-64: per-wave top-64 (no barriers), then 8-way merge =====
  __shared__ float cval[8 * KNEG];      // per-wave sorted top-64 lists
  __shared__ int   cidx[8 * KNEG];
  __shared__ int   topidx[KNEG];

  // lane-local: load 8 (val, idx), sort desc via 19-CE Batcher network
  float v0 = norms[e*N_ROWS + 0*512 + t], v1 = norms[e*N_ROWS + 1*512 + t];
  float v2 = norms[e*N_ROWS + 2*512 + t], v3 = norms[e*N_ROWS + 3*512 + t];
  float v4 = norms[e*N_ROWS + 4*512 + t], v5 = norms[e*N_ROWS + 5*512 + t];
  float v6 = norms[e*N_ROWS + 6*512 + t], v7 = norms[e*N_ROWS + 7*512 + t];
  int d0 = 0*512+t, d1 = 1*512+t, d2 = 2*512+t, d3 = 3*512+t;
  int d4 = 4*512+t, d5 = 5*512+t, d6 = 6*512+t, d7 = 7*512+t;
  CE(0,1) CE(2,3) CE(4,5) CE(6,7)
  CE(0,2) CE(1,3) CE(4,6) CE(5,7)
  CE(1,2) CE(5,6)
  CE(0,4) CE(1,5) CE(2,6) CE(3,7)
  CE(2,4) CE(3,5)
  CE(1,2) CE(3,4) CE(5,6)

  // wave pops its global max 64 times (wave-synchronous, no barriers)
  for (int k = 0; k < KNEG; ++k) {
    float bv = v0; int bi = d0;
#pragma unroll
    for (int off = 32; off; off >>= 1) {
      float ov = __shfl_xor(bv, off);
      int   oi = __shfl_xor(bi, off);
      if (ov > bv || (ov == bv && oi < bi)) { bv = ov; bi = oi; }
    }
    if (lane == 0) { cval[w * KNEG + k] = bv; cidx[w * KNEG + k] = bi; }
    if (v0 == bv && d0 == bi) {          // winner lane shifts its list down
      v0=v1; d0=d1; v1=v2; d1=d2; v2=v3; d2=d3; v3=v4; d3=d4;
      v4=v5; d4=d5; v5=v6; d5=d6; v6=v7; d6=d7; v7=NEGINF; d7=0x7fffffff;
    }
  }
  __syncthreads();

  // lanes 0-7 of wave 0: 64-step 8-way merge of the sorted lists
  if (w == 0) {
    int p = 0;
    float hv = (lane < 8) ? cval[lane * KNEG] : NEGINF;
    int   hi = (lane < 8) ? cidx[lane * KNEG] : 0x7fffffff;
    for (int k = 0; k < KNEG; ++k) {
      float bv = hv; int bi = hi;
#pragma unroll
      for (int off = 4; off; off >>= 1) {          // butterfly within 8 lanes
        float ov = __shfl_xor(bv, off, 8);
        int   oi = __shfl_xor(bi, off, 8);
        if (ov > bv || (ov == bv && oi < bi)) { bv = ov; bi = oi; }
      }
      if (lane == 0) topidx[k] = bi;
      if (lane < 8 && hv == bv && hi == bi) {      // winner list advances
        ++p;
        hv = (p < KNEG) ? cval[lane * KNEG + p] : NEGINF;
        hi = (p < KNEG) ? cidx[lane * KNEG + p] : 0x7fffffff;
      }
    }
  }
  __syncthreads();

  // ---- fold partials -> sums (batched: 16 loads in flight) ----
  float s = 0.f;
  {
    float x[BPE];
#pragma unroll
    for (int b2 = 0; b2 < BPE; ++b2)
      x[b2] = partial[(size_t)(e * BPE + b2) * DIM + t];
#pragma unroll
    for (int b2 = 0; b2 < BPE; ++b2) s += x[b2];
  }

  // ---- gather top-64 rows (nt, batched 16 rows in flight), subtract ----
  const float* base = I + (size_t)e * N_ROWS * DIM;
  float a = 0.f;
  for (int k0 = 0; k0 < KNEG; k0 += 16) {
    float x[16];
#pragma unroll
    for (int q = 0; q < 16; ++q)
      x[q] = __builtin_nontemporal_load(base + (size_t)topidx[k0 + q] * DIM + t);
#pragma unroll
    for (int q = 0; q < 16; ++q) a += x[q];
  }
  float sn = s - a;

  // ---- norms of both sample rows ----
  float q1 = s * s, q2 = sn * sn;
#pragma unroll
  for (int off = 32; off; off >>= 1) {
    q1 += __shfl_xor(q1, off);
    q2 += __shfl_xor(q2, off);
  }
  if (lane == 0) { rA[w] = q1; rB[w] = q2; }
  __syncthreads();
  if (t == 0) {
    float n1 = 0.f, n2 = 0.f;
    for (int q = 0; q < 8; ++q) { n1 += rA[q]; n2 += rB[q]; }
    snorm[e]         = fmaxf(sqrtf(n1), EPSN);
    snorm[D_EMB + e] = fmaxf(sqrtf(n2), EPSN);
  }
  samples[(size_t)e * DIM + t]           = s;
  samples[(size_t)(D_EMB + e) * DIM + t] = sn;
}

// ---------------- kernel 3: select + sims + LSE + loss + final sum ----------
__global__ __launch_bounds__(256) void k_p3p4(const float* __restrict__ samples,
                                              const float* __restrict__ snorm,
                                              const float* __restrict__ posp,
                                              float* __restrict__ pairloss,
                                              int* __restrict__ cnt2,
                                              float* __restrict__ out) {
  const int p = blockIdx.x;
  const int t = threadIdx.x, lane = t & 63, w = t >> 6;
  __shared__ uint32_t bits[126];
  __shared__ uint32_t sk[2];
  __shared__ int      sel[KNEG];
  __shared__ float    simi[KNEG], simj[KNEG];
  __shared__ int      flag;

  if (t == 0) {
    uint32_t kh, kl, a, b;
    threefry(0u, 42u, 0u, (uint32_t)p, kh, kl);   // keys[p] = split(key(42),62)[p]
    threefry(kh, kl, 0u, 1u, a, b);               // subkey = split(keys[p])[1]
    sk[0] = a; sk[1] = b;
  }
  __syncthreads();
  if (t < 126) {
    uint32_t a, b;
    threefry(sk[0], sk[1], 0u, (uint32_t)t, a, b);
    bits[t] = a ^ b;                              // partitionable 32-bit path
  }
  __syncthreads();
  if (t < 126) {
    const uint32_t myb = bits[t];
    int rank = 0;
    for (int j = 0; j < 126; ++j) {
      const uint32_t bj = bits[j];
      rank += ((bj < myb) || (bj == myb && j < t)) ? 1 : 0;
    }
    if (rank < KNEG) {
      int vv = t + (t >= p ? 1 : 0);              // cand mapping: skip i=p
      vv += (vv >= p + 2 ? 1 : 0);                // then skip j=p+2
      sel[rank] = vv;
    }
  }
  __syncthreads();

  const float4* S = reinterpret_cast<const float4*>(samples);
  const float4 siA = S[p * 128 + lane],       siB = S[p * 128 + 64 + lane];
  const float4 sjA = S[(p + 2) * 128 + lane], sjB = S[(p + 2) * 128 + 64 + lane];
  const float ni = snorm[p], nj = snorm[p + 2];
  for (int k = w; k < KNEG; k += 4) {
    const int r = sel[k];
    const float4 vA = S[r * 128 + lane], vB = S[r * 128 + 64 + lane];
    float di = siA.x*vA.x + siA.y*vA.y + siA.z*vA.z + siA.w*vA.w
             + siB.x*vB.x + siB.y*vB.y + siB.z*vB.z + siB.w*vB.w;
    float dj = sjA.x*vA.x + sjA.y*vA.y + sjA.z*vA.z + sjA.w*vA.w
             + sjB.x*vB.x + sjB.y*vB.y + sjB.z*vB.z + sjB.w*vB.w;
#pragma unroll
    for (int off = 32; off; off >>= 1) {
      di += __shfl_xor(di, off);
      dj += __shfl_xor(dj, off);
    }
    if (lane == 0) {
      const float nr = snorm[r];
      simi[k] = di / (ni * nr) * INV_T;
      simj[k] = dj / (nj * nr) * INV_T;
    }
  }
  __syncthreads();
  if (t < KNEG) {                                  // wave 0 only
    const float xi = simi[t], xj = simj[t];
    float mi = xi, mj = xj;
#pragma unroll
    for (int off = 32; off; off >>= 1) {
      mi = fmaxf(mi, __shfl_xor(mi, off));
      mj = fmaxf(mj, __shfl_xor(mj, off));
    }
    float ei = expf(xi - mi), ej = expf(xj - mj);
#pragma unroll
    for (int off = 32; off; off >>= 1) {
      ei += __shfl_xor(ei, off);
      ej += __shfl_xor(ej, off);
    }
    if (t == 0) {
      const float pos = posp[0];
      const float lsei = mi + logf(ei), lsej = mj + logf(ej);
      const float li = fmaxf(pos, lsei) + log1pf(expf(-fabsf(pos - lsei))) - pos;
      const float lj = fmaxf(pos, lsej) + log1pf(expf(-fabsf(pos - lsej))) - pos;
      pairloss[p] = li + lj;
    }
  }
  __syncthreads();

  // ---- last-arriving pair block does the final sum ----
  if (t == 0) {
    int old = __hip_atomic_fetch_add(cnt2, 1, __ATOMIC_ACQ_REL,
                                     __HIP_MEMORY_SCOPE_AGENT);
    flag = (old == P_PAIRS - 1) ? 1 : 0;
  }
  __syncthreads();
  const int trig = flag;
  __syncthreads();
  if (!trig) return;
  __builtin_amdgcn_fence(__ATOMIC_ACQUIRE, "agent");
  if (t < 64) {
    float vv = (t < P_PAIRS) ? pairloss[t] : 0.f;
#pragma unroll
    for (int off = 32; off; off >>= 1) vv += __shfl_xor(vv, off);
    if (t == 0) out[0] = vv;
  }
}

extern "C" void kernel_launch(void* const* d_in, const int* in_sizes, int n_in,
                              void* d_out, int out_size, void* d_ws, size_t ws_size,
                              hipStream_t stream) {
  const float* I  = (const float*)d_in[0];
  const float* g1 = (const float*)d_in[2];
  const float* g2 = (const float*)d_in[3];
  float* out = (float*)d_out;

  float* ws = (float*)d_ws;
  float* norms    = ws;                                   // 64*4096     = 262144
  float* partial  = ws + 262144;                          // 1024*512    = 524288
  float* samples  = partial + 524288;                     // 128*512     = 65536
  float* snorm    = samples + 65536;                      // 128
  float* posp     = snorm + 128;                          // 1 (+pad)
  float* pairloss = posp + 4;                             // 62 (+pad 64)
  int*   cnt2     = (int*)(pairloss + 64);                // 1 int (zeroed by k_embed)

  k_pass1<<<NCHUNK,    256, 0, stream>>>(I, partial, norms);
  k_embed<<<D_EMB + 1, 512, 0, stream>>>(I, partial, norms, g1, g2,
                                         samples, snorm, posp, cnt2);
  k_p3p4 <<<P_PAIRS,   256, 0, stream>>>(samples, snorm, posp, pairloss,
                                         cnt2, out);
}